// Round 1
// baseline (316.197 us; speedup 1.0000x reference)
//
#include <hip/hip_runtime.h>
#include <hip/hip_bf16.h>
#include <stdint.h>

// Problem constants (B,T,C) = (4,4096,1024)
#define TT 4096
#define BB 4
#define CC 1024
#define MM (BB * TT)          // 16384 rows
#define NCHUNK 64             // scan chunks along T
#define CHUNK_T (TT / NCHUNK) // 64 steps per chunk
#define NCHAIN (BB * CC)      // 4096 independent scan chains

typedef float f32x4 __attribute__((ext_vector_type(4)));
typedef __bf16 bf16x8 __attribute__((ext_vector_type(8)));

__device__ __forceinline__ float b2f(ushort u) {
  union { float f; uint32_t v; } x; x.v = ((uint32_t)u) << 16; return x.f;
}
__device__ __forceinline__ ushort f2b(float f) { // RNE fp32->bf16
  union { float f; uint32_t u; } x; x.f = f;
  uint32_t r = x.u + 0x7fffu + ((x.u >> 16) & 1u);
  return (ushort)(r >> 16);
}

// async global->LDS, 16B per lane. LDS dest must be uniform-base + lane*16.
__device__ __forceinline__ void async_copy16(const ushort* g, ushort* l) {
  __builtin_amdgcn_global_load_lds(
      (__attribute__((address_space(1))) void*)(g),
      (__attribute__((address_space(3))) void*)(l), 16, 0, 0);
}

__global__ __launch_bounds__(256) void cvt_f32_bf16(const float* __restrict__ s,
                                                    ushort* __restrict__ d, int n4) {
  int i = blockIdx.x * 256 + threadIdx.x;
  if (i >= n4) return;
  float4 v = ((const float4*)s)[i];
  ushort4 o;
  o.x = f2b(v.x); o.y = f2b(v.y); o.z = f2b(v.z); o.w = f2b(v.w);
  ((ushort4*)d)[i] = o;
}

// C[m][n] = sum_k A[m][k] * Bw[n][k]   (both row-major, K contiguous; K=1024)
// MODE 0: write fp32 to outF[m*N+n]
// MODE 1: gates epilogue -> n<1024: sigmoid (f), n>=1024: tanh (g); write bf16 to outB[m*N+n]
template <int MODE>
__global__ __launch_bounds__(256) void gemm_bt(const ushort* __restrict__ A,
                                               const ushort* __restrict__ Bw,
                                               float* __restrict__ outF,
                                               ushort* __restrict__ outB, int N) {
  constexpr int K = CC;
  __shared__ __align__(16) ushort sA[128 * 32];
  __shared__ __align__(16) ushort sB[128 * 32];
  const int tid = threadIdx.x;
  const int lane = tid & 63;
  const int wid = tid >> 6;      // 4 waves: 2x2 over the 128x128 tile
  const int wm = wid >> 1, wn = wid & 1;
  const long m0 = (long)blockIdx.y * 128;
  const long n0 = (long)blockIdx.x * 128;

  f32x4 acc[4][4];
#pragma unroll
  for (int i = 0; i < 4; ++i)
#pragma unroll
    for (int j = 0; j < 4; ++j) acc[i][j] = (f32x4){0.f, 0.f, 0.f, 0.f};

  // staging: each 1KB wave-chunk = 16 rows x 32 bf16; lane -> (row=lane/4, col=(lane%4)*8)
  const int srow = lane >> 2;
  const int scol = (lane & 3) * 8;
  const ushort* Ab = A + (m0 + srow) * K + scol;
  const ushort* Bb = Bw + (n0 + srow) * K + scol;

  for (int k0 = 0; k0 < K; k0 += 32) {
#pragma unroll
    for (int half = 0; half < 2; ++half) {
      const int ch = wid + half * 4;                 // chunks 0..7
      async_copy16(Ab + (long)ch * 16 * K + k0, &sA[ch * 512 + lane * 8]);
      async_copy16(Bb + (long)ch * 16 * K + k0, &sB[ch * 512 + lane * 8]);
    }
    __syncthreads(); // drains vmcnt (compiler inserts) then barrier

    const int kq = lane >> 4; // k-quad: k = kq*8 + j
    bf16x8 af[4], bfr[4];
#pragma unroll
    for (int i = 0; i < 4; ++i) {
      af[i]  = *(const bf16x8*)&sA[(wm * 64 + i * 16 + (lane & 15)) * 32 + kq * 8];
      bfr[i] = *(const bf16x8*)&sB[(wn * 64 + i * 16 + (lane & 15)) * 32 + kq * 8];
    }
#pragma unroll
    for (int i = 0; i < 4; ++i)
#pragma unroll
      for (int j = 0; j < 4; ++j)
        acc[i][j] = __builtin_amdgcn_mfma_f32_16x16x32_bf16(af[i], bfr[j], acc[i][j], 0, 0, 0);
    __syncthreads();
  }

  // C/D layout (m89-verified): col = lane&15, row = (lane>>4)*4 + r
  const int col = lane & 15;
  const int rq = lane >> 4;
#pragma unroll
  for (int i = 0; i < 4; ++i) {
#pragma unroll
    for (int j = 0; j < 4; ++j) {
      const long n = n0 + wn * 64 + j * 16 + col;
#pragma unroll
      for (int r = 0; r < 4; ++r) {
        const long m = m0 + wm * 64 + i * 16 + rq * 4 + r;
        float v = acc[i][j][r];
        if (MODE == 0) {
          outF[m * N + n] = v;
        } else {
          float act;
          if (n < CC) {
            act = 1.f / (1.f + __expf(-v));            // f = sigmoid
          } else {
            float e = __expf(2.f * v);                  // g = tanh
            act = (e - 1.f) / (e + 1.f);
          }
          outB[m * (long)N + n] = f2b(act);
        }
      }
    }
  }
}

// P layout: [m=b*T+t][0..1023]=f (bf16), [1024..2047]=g (bf16); recurrence a=f, b=(1-f)*g
__global__ __launch_bounds__(256) void scan_pass1(const ushort* __restrict__ P,
                                                  float* __restrict__ cA,
                                                  float* __restrict__ cB) {
  const int chain = blockIdx.x * 256 + threadIdx.x; // 0..4095
  const int chunk = blockIdx.y;
  const int b = chain >> 10, c = chain & (CC - 1);
  const ushort* p = P + (size_t)(b * TT + chunk * CHUNK_T) * (2 * CC) + c;
  float A = 1.f, h = 0.f;
#pragma unroll 4
  for (int i = 0; i < CHUNK_T; ++i) {
    const float f = b2f(p[0]);
    const float g = b2f(p[CC]);
    p += 2 * CC;
    A *= f;
    h = fmaf(f, h, (1.f - f) * g);
  }
  cA[chunk * NCHAIN + chain] = A;
  cB[chunk * NCHAIN + chain] = h;
}

__global__ __launch_bounds__(256) void scan_pass2(const float* __restrict__ cA,
                                                  const float* __restrict__ cB,
                                                  float* __restrict__ hinit) {
  const int chain = blockIdx.x * 256 + threadIdx.x;
  float h = 0.f;
  for (int j = 0; j < NCHUNK; ++j) {
    hinit[j * NCHAIN + chain] = h; // exclusive carry
    h = fmaf(cA[j * NCHAIN + chain], h, cB[j * NCHAIN + chain]);
  }
}

__global__ __launch_bounds__(256) void scan_pass3(const ushort* __restrict__ P,
                                                  const float* __restrict__ hinit,
                                                  ushort* __restrict__ H) {
  const int chain = blockIdx.x * 256 + threadIdx.x;
  const int chunk = blockIdx.y;
  const int b = chain >> 10, c = chain & (CC - 1);
  const ushort* p = P + (size_t)(b * TT + chunk * CHUNK_T) * (2 * CC) + c;
  ushort* hp = H + (size_t)(b * TT + chunk * CHUNK_T) * CC + c;
  float h = hinit[chunk * NCHAIN + chain];
#pragma unroll 4
  for (int i = 0; i < CHUNK_T; ++i) {
    const float f = b2f(p[0]);
    const float g = b2f(p[CC]);
    p += 2 * CC;
    h = fmaf(f, h, (1.f - f) * g);
    *hp = f2b(h);
    hp += CC;
  }
}

extern "C" void kernel_launch(void* const* d_in, const int* in_sizes, int n_in,
                              void* d_out, int out_size, void* d_ws, size_t ws_size,
                              hipStream_t stream) {
  const float* x  = (const float*)d_in[0];
  const float* Wf = (const float*)d_in[1];
  const float* Wg = (const float*)d_in[2];
  const float* Wp = (const float*)d_in[3];

  // workspace layout (bytes); H aliases xb (xb dead after gates GEMM, stream-ordered)
  char* ws = (char*)d_ws;
  ushort* xb   = (ushort*)(ws);                                  // 33554432 B
  ushort* Hb   = xb;                                             // alias
  ushort* Wcat = (ushort*)(ws + 33554432);                       //  4194304 B (Wf||Wg)
  ushort* Wpb  = (ushort*)(ws + 33554432 + 4194304);             //  2097152 B
  ushort* P    = (ushort*)(ws + 33554432 + 4194304 + 2097152);   // 67108864 B (f||g bf16)
  char* tail   = ws + 33554432 + 4194304 + 2097152 + 67108864;
  float* cA    = (float*)(tail);                                 // 1 MiB
  float* cB    = (float*)(tail + 1048576);                       // 1 MiB
  float* hinit = (float*)(tail + 2097152);                       // 1 MiB
  (void)ws_size; (void)in_sizes; (void)n_in; (void)out_size;

  // 1) fp32 -> bf16 conversions
  cvt_f32_bf16<<<MM * CC / 4 / 256, 256, 0, stream>>>(x, xb, MM * CC / 4);
  cvt_f32_bf16<<<CC * CC / 4 / 256, 256, 0, stream>>>(Wf, Wcat, CC * CC / 4);
  cvt_f32_bf16<<<CC * CC / 4 / 256, 256, 0, stream>>>(Wg, Wcat + CC * CC, CC * CC / 4);
  cvt_f32_bf16<<<CC * CC / 4 / 256, 256, 0, stream>>>(Wp, Wpb, CC * CC / 4);

  // 2) gates GEMM: [16384 x 2048] = xb @ Wcat^T, fused sigmoid/tanh epilogue -> P (bf16)
  dim3 g1(2 * CC / 128, MM / 128);
  gemm_bt<1><<<g1, 256, 0, stream>>>(xb, Wcat, nullptr, P, 2 * CC);

  // 3) chunked scan: h_t = f*h + (1-f)*g, write H (bf16)
  dim3 gs(NCHAIN / 256, NCHUNK);
  scan_pass1<<<gs, 256, 0, stream>>>(P, cA, cB);
  scan_pass2<<<NCHAIN / 256, 256, 0, stream>>>(cA, cB, hinit);
  scan_pass3<<<gs, 256, 0, stream>>>(P, hinit, Hb);

  // 4) projection GEMM: out[16384 x 1024] = H @ Wp^T (fp32 out)
  dim3 g3(CC / 128, MM / 128);
  gemm_bt<0><<<g3, 256, 0, stream>>>(Hb, Wpb, (float*)d_out, nullptr, CC);
}